// Round 11
// baseline (768.065 us; speedup 1.0000x reference)
//
#include <hip/hip_runtime.h>
#include <hip/hip_bf16.h>
#include <math.h>

#define TPTS 96
#define CTOT 128
#define LDP 134   // LDS row pitch u16: <=2-way banks (verified R4: conflicts ~0)

typedef __bf16 bf16x8_t __attribute__((ext_vector_type(8)));
typedef float f32x4_t __attribute__((ext_vector_type(4)));
typedef unsigned short us8_t __attribute__((ext_vector_type(8)));

__device__ __forceinline__ unsigned short f2b(float f) {
    union { float f; unsigned int i; } v; v.f = f;
    unsigned int r = v.i + 0x7fffu + ((v.i >> 16) & 1u);
    return (unsigned short)(r >> 16);
}
// HW packed bf16 convert (RNE, bit-identical to f2b for finite inputs):
// 1 instr replaces ~11 of manual bit-twiddling. (R6)
__device__ __forceinline__ unsigned int packbf2(float a, float b) {
    unsigned int r;
    asm("v_cvt_pk_bf16_f32 %0, %1, %2" : "=v"(r) : "v"(a), "v"(b));
    return r;
}
__device__ __forceinline__ uint2 pack4(float v0, float v1, float v2, float v3) {
    uint2 w; w.x = packbf2(v0, v1); w.y = packbf2(v2, v3); return w;
}
__device__ __forceinline__ f32x4_t mfma16(bf16x8_t a, bf16x8_t b, f32x4_t c) {
    return __builtin_amdgcn_mfma_f32_16x16x32_bf16(a, b, c, 0, 0, 0);
}
__device__ __forceinline__ bf16x8_t ldfrag(const unsigned short* p) {
    us8_t v = *(const us8_t*)p;
    return __builtin_bit_cast(bf16x8_t, v);
}
// Cross-XCD coherent fragment load: relaxed agent atomics -> plain
// global_load_dwordx2 sc0/sc1 (bypass stale L1/L2, served from LLC).
__device__ __forceinline__ bf16x8_t ldfragG(const unsigned short* p) {
    union { unsigned long long q[2]; us8_t v; } u;
    u.q[0] = __hip_atomic_load((const unsigned long long*)p,
                               __ATOMIC_RELAXED, __HIP_MEMORY_SCOPE_AGENT);
    u.q[1] = __hip_atomic_load((const unsigned long long*)(p + 4),
                               __ATOMIC_RELAXED, __HIP_MEMORY_SCOPE_AGENT);
    return __builtin_bit_cast(bf16x8_t, u.v);
}
// Cross-XCD coherent 8B store: write-through to LLC (chip coherence point).
__device__ __forceinline__ void stg8(unsigned short* p, uint2 pk) {
    unsigned long long q = ((unsigned long long)pk.y << 32) | (unsigned long long)pk.x;
    __hip_atomic_store((unsigned long long*)p, q,
                       __ATOMIC_RELAXED, __HIP_MEMORY_SCOPE_AGENT);
}
__device__ __forceinline__ bf16x8_t ldfragW(const float* p) {
    float4 a = *(const float4*)p;
    float4 b = *(const float4*)(p + 4);
    bf16x8_t r;
    r[0] = __builtin_bit_cast(__bf16, f2b(a.x)); r[1] = __builtin_bit_cast(__bf16, f2b(a.y));
    r[2] = __builtin_bit_cast(__bf16, f2b(a.z)); r[3] = __builtin_bit_cast(__bf16, f2b(a.w));
    r[4] = __builtin_bit_cast(__bf16, f2b(b.x)); r[5] = __builtin_bit_cast(__bf16, f2b(b.y));
    r[6] = __builtin_bit_cast(__bf16, f2b(b.z)); r[7] = __builtin_bit_cast(__bf16, f2b(b.w));
    return r;
}
__device__ __forceinline__ float tanh2(float x) {   // finite inputs only
    float e = __expf(x + x);
    return 1.f - __fdividef(2.f, e + 1.f);
}
__device__ __forceinline__ float sigm(float x) {
    return __fdividef(1.f, 1.f + __expf(-x));
}

// Raw barrier: LDS-drain only. __syncthreads() would also s_waitcnt vmcnt(0),
// putting the ~700-900cy LLC store-ack on the serial path; our global stores
// instead drain lazily at an explicit vmcnt(0) placed 1-2 stages later, where
// the ack has long arrived. The asm "memory" clobber is the compiler fence.
#define LGKM_BAR() do {                                         \
        asm volatile("s_waitcnt lgkmcnt(0)" ::: "memory");      \
        __builtin_amdgcn_s_barrier();                           \
    } while (0)

// role-2 consumer poll (role-1 has the release/spin inlined for flag deferral)
__device__ __forceinline__ void waitflag(unsigned int* f, unsigned int want) {
    if (threadIdx.x == 0) {
        int guard = 0;
        while (__hip_atomic_load(f, __ATOMIC_RELAXED, __HIP_MEMORY_SCOPE_AGENT) != want) {
            __builtin_amdgcn_s_sleep(1);
            if (++guard > (1 << 22)) break;   // hang-proof: degrade, don't wedge
        }
    }
    __syncthreads();
}
__device__ __forceinline__ void setflag(unsigned int* f, unsigned int val) {
    if (threadIdx.x == 0) {
        asm volatile("s_waitcnt vmcnt(0)" ::: "memory");  // data globally visible first
        __hip_atomic_store(f, val, __ATOMIC_RELAXED, __HIP_MEMORY_SCOPE_AGENT);
    }
}

// R15 = Round-2 kernel VERBATIM (session best: 760.6us harness / 683us
// counters). Rounds 9-10 (16-wave 4/SIMD variant) died twice in the container;
// every 512-thread kernel ran fine, so that arm is abandoned and the best
// proven configuration is banked. 192 blocks x 512 thr: role = blockIdx>>6
// (0:ODE producer, 1:GRU0, 2:GRU1+head). Each role-c block owns rows
// [16c,16c+16). ODE critical path = 570 stages; GRU consumers run
// concurrently on other CUs, lagging behind their feed.
__global__ void __launch_bounds__(512, 2)
ode_forecaster(const float* __restrict__ yl,
               const float* __restrict__ yh,
               const float* __restrict__ Wode,
               const float* __restrict__ bode,
               const float* __restrict__ Wih0,
               const float* __restrict__ Whh0,
               const float* __restrict__ bih0,
               const float* __restrict__ bhh0,
               const float* __restrict__ Wih1,
               const float* __restrict__ Whh1,
               const float* __restrict__ bih1,
               const float* __restrict__ bhh1,
               const float* __restrict__ W1v,
               const float* __restrict__ b1v,
               const float* __restrict__ W2v,
               const float* __restrict__ b2v,
               float* __restrict__ outp,
               char* __restrict__ wsb)
{
    const int role = blockIdx.x >> 6;
    const int c    = blockIdx.x & 63;
    const int tid  = threadIdx.x, lane = tid & 63, wv = tid >> 6;
    const int l15  = lane & 15, quad = lane >> 4;
    const int fbase = wv * 16 + quad * 4;
    const int rbase = c * 16;

    __shared__ __align__(16) unsigned short zbuf[2][16][LDP];
    __shared__ __align__(16) unsigned short hidbuf[16][72];

    unsigned short* yTraj  = (unsigned short*)(wsb);
    unsigned short* h1Traj = (unsigned short*)(wsb + 0x2000000);
    unsigned int*   yflag  = (unsigned int*)(wsb + 0x4000000);
    unsigned int*   h1flag = (unsigned int*)(wsb + 0x4010000);
#define YMAGIC(t)  (0x5E000000u + (unsigned)(t))
#define H1MAGIC(t) (0x6E000000u + (unsigned)(t))

    if (role == 0) {
        // ================= ODE producer (the serial critical path) ===========
        bf16x8_t wode[4];
#pragma unroll
        for (int kt = 0; kt < 4; ++kt)
            wode[kt] = ldfragW(Wode + (wv * 16 + l15) * CTOT + kt * 32 + quad * 8);
        float bo2[4];   // 2*bias, folded into the exp argument via one FMA
        {
            float4 b4 = *(const float4*)(bode + fbase);
            bo2[0] = 2.f * b4.x; bo2[1] = 2.f * b4.y; bo2[2] = 2.f * b4.z; bo2[3] = 2.f * b4.w;
        }
        float y[4];
        {
            int row = rbase + l15;
#pragma unroll
            for (int i = 0; i < 4; ++i) {
                int f = fbase + i;
                y[i] = (f < 32) ? yl[row * 32 + f] : yh[row * 96 + (f - 32)];
            }
            uint2 pk = pack4(y[0], y[1], y[2], y[3]);
            *(uint2*)&zbuf[0][l15][fbase] = pk;
            stg8(yTraj + ((size_t)row) * CTOT + fbase, pk);
        }
        __syncthreads();                      // full drain (once, pre-loop)
        setflag(&yflag[c * 128 + 0], YMAGIC(0));

        // dt-folded Dormand-Prince coefficients
        const float dt = 1.0f / 95.0f;
        const float d10 = dt * 0.2f;
        const float d20 = dt * (3.f/40.f),  d21 = dt * (9.f/40.f);
        const float d30 = dt * (44.f/45.f), d31 = dt * (-56.f/15.f), d32 = dt * (32.f/9.f);
        const float d40 = dt * (19372.f/6561.f), d41 = dt * (-25360.f/2187.f),
                    d42 = dt * (64448.f/6561.f), d43 = dt * (-212.f/729.f);
        const float d50 = dt * (9017.f/3168.f), d51 = dt * (-355.f/33.f),
                    d52 = dt * (46732.f/5247.f), d53 = dt * (49.f/176.f),
                    d54 = dt * (-5103.f/18656.f);
        const float e0 = dt * (35.f/384.f), e2 = dt * (500.f/1113.f), e3 = dt * (125.f/192.f),
                    e4 = dt * (-2187.f/6784.f), e5 = dt * (11.f/84.f);

        int p = 0;
        float kr[6][4];
#pragma unroll 1
        for (int t = 0; t < 95; ++t) {
#pragma unroll
            for (int s = 0; s < 6; ++s) {
                bf16x8_t bf[4];
#pragma unroll
                for (int kt = 0; kt < 4; ++kt)
                    bf[kt] = ldfrag(&zbuf[p][l15][kt * 32 + quad * 8]);
                // 4 independent accumulators + tree add: 1-deep MFMA chain
                const f32x4_t zz = {0.f, 0.f, 0.f, 0.f};
                f32x4_t a0 = mfma16(wode[0], bf[0], zz);
                f32x4_t a1 = mfma16(wode[1], bf[1], zz);
                f32x4_t a2 = mfma16(wode[2], bf[2], zz);
                f32x4_t a3 = mfma16(wode[3], bf[3], zz);
                f32x4_t acc = (a0 + a1) + (a2 + a3);
#pragma unroll
                for (int i = 0; i < 4; ++i) {
                    float e = __expf(fmaf(acc[i], 2.f, bo2[i]));   // exp(2*(acc+bo))
                    kr[s][i] = 1.f - __fdividef(2.f, e + 1.f);
                }

                if (s < 5) {
                    float z[4];
#pragma unroll
                    for (int i = 0; i < 4; ++i) {
                        float zv;
                        if (s == 0)      zv = y[i] + d10 * kr[0][i];
                        else if (s == 1) zv = y[i] + d20 * kr[0][i] + d21 * kr[1][i];
                        else if (s == 2) zv = y[i] + d30 * kr[0][i] + d31 * kr[1][i] + d32 * kr[2][i];
                        else if (s == 3) zv = y[i] + d40 * kr[0][i] + d41 * kr[1][i]
                                             + d42 * kr[2][i] + d43 * kr[3][i];
                        else             zv = y[i] + d50 * kr[0][i] + d51 * kr[1][i]
                                             + d52 * kr[2][i] + d53 * kr[3][i] + d54 * kr[4][i];
                        z[i] = zv;
                    }
                    *(uint2*)&zbuf[p ^ 1][l15][fbase] = pack4(z[0], z[1], z[2], z[3]);
                } else {
#pragma unroll
                    for (int i = 0; i < 4; ++i)
                        y[i] += e0*kr[0][i] + e2*kr[2][i] + e3*kr[3][i] + e4*kr[4][i] + e5*kr[5][i];
                    uint2 pk = pack4(y[0], y[1], y[2], y[3]);
                    *(uint2*)&zbuf[p ^ 1][l15][fbase] = pk;
                    // issue the trajectory store; it drains (vmcnt) 2 stages
                    // later at s==1 of t+1, where the LLC ack has long landed.
                    stg8(yTraj + ((size_t)(t + 1) * 1024 + rbase + l15) * CTOT + fbase, pk);
                }
                if (s == 1)   // deferred-drain point for the store issued at t-1,s5
                    asm volatile("s_waitcnt vmcnt(0)" ::: "memory");
                LGKM_BAR();
                if (s == 1 && t > 0 && tid == 0)
                    __hip_atomic_store(&yflag[c * 128 + t], YMAGIC(t),
                                       __ATOMIC_RELAXED, __HIP_MEMORY_SCOPE_AGENT);
                p ^= 1;
            }
        }
        // final flag (y[95] stored at t=94,s5)
        asm volatile("s_waitcnt vmcnt(0)" ::: "memory");
        __builtin_amdgcn_s_barrier();
        if (tid == 0)
            __hip_atomic_store(&yflag[c * 128 + 95], YMAGIC(95),
                               __ATOMIC_RELAXED, __HIP_MEMORY_SCOPE_AGENT);
        return;
    }

    // ==================== GRU consumer roles ==================================
    const float* Wih = (role == 1) ? Wih0 : Wih1;
    const float* Whh = (role == 1) ? Whh0 : Whh1;
    const float* bih = (role == 1) ? bih0 : bih1;
    const float* bhh = (role == 1) ? bhh0 : bhh1;
    const unsigned short* src = (role == 1) ? yTraj : h1Traj;
    unsigned int* sflag = (role == 1) ? yflag : h1flag;

    bf16x8_t wih[3][4], whh[3][4];
#pragma unroll
    for (int g = 0; g < 3; ++g)
#pragma unroll
        for (int kt = 0; kt < 4; ++kt) {
            wih[g][kt] = ldfragW(Wih + (size_t)(g * 128 + wv * 16 + l15) * CTOT + kt * 32 + quad * 8);
            whh[g][kt] = ldfragW(Whh + (size_t)(g * 128 + wv * 16 + l15) * CTOT + kt * 32 + quad * 8);
        }
    float br[4], bz[4], bin_[4], bhn[4];
    {
        float4 a0 = *(const float4*)(bih + 0 * 128 + fbase);
        float4 b0 = *(const float4*)(bhh + 0 * 128 + fbase);
        float4 a1 = *(const float4*)(bih + 1 * 128 + fbase);
        float4 b1 = *(const float4*)(bhh + 1 * 128 + fbase);
        float4 a2 = *(const float4*)(bih + 2 * 128 + fbase);
        float4 b2 = *(const float4*)(bhh + 2 * 128 + fbase);
        br[0] = a0.x + b0.x; br[1] = a0.y + b0.y; br[2] = a0.z + b0.z; br[3] = a0.w + b0.w;
        bz[0] = a1.x + b1.x; bz[1] = a1.y + b1.y; bz[2] = a1.z + b1.z; bz[3] = a1.w + b1.w;
        bin_[0] = a2.x; bin_[1] = a2.y; bin_[2] = a2.z; bin_[3] = a2.w;
        bhn[0] = b2.x; bhn[1] = b2.y; bhn[2] = b2.z; bhn[3] = b2.w;
    }

    float h[4] = {0.f, 0.f, 0.f, 0.f};
    *(uint2*)&zbuf[0][l15][fbase] = pack4(0.f, 0.f, 0.f, 0.f);
    int p = 0;
    __syncthreads();

    if (role == 1) {
        // GRU0: deferred h1-flag release — t-1's store drains during t's flag
        // wait (dead time), so no vmcnt(0) ever sits on the compute path.
#pragma unroll 1
        for (int t = 0; t < TPTS; ++t) {
            asm volatile("s_waitcnt vmcnt(0)" ::: "memory");   // drain t-1 store (free by now)
            __builtin_amdgcn_s_barrier();                      // all waves drained
            if (tid == 0) {
                if (t > 0)
                    __hip_atomic_store(&h1flag[c * 128 + (t - 1)], H1MAGIC(t - 1),
                                       __ATOMIC_RELAXED, __HIP_MEMORY_SCOPE_AGENT);
                int guard = 0;
                while (__hip_atomic_load(&yflag[c * 128 + t],
                                         __ATOMIC_RELAXED, __HIP_MEMORY_SCOPE_AGENT) != YMAGIC(t)) {
                    __builtin_amdgcn_s_sleep(1);
                    if (++guard > (1 << 22)) break;
                }
            }
            __syncthreads();
            const unsigned short* xp = src + ((size_t)t * 1024 + rbase + l15) * CTOT;
            bf16x8_t ax[4], ah[4];
#pragma unroll
            for (int kt = 0; kt < 4; ++kt) {
                ax[kt] = ldfragG(xp + kt * 32 + quad * 8);
                ah[kt] = ldfrag(&zbuf[p][l15][kt * 32 + quad * 8]);
            }
            f32x4_t gx[3], gh[3];
#pragma unroll
            for (int g = 0; g < 3; ++g) {
                gx[g] = (f32x4_t){0.f, 0.f, 0.f, 0.f};
                gh[g] = (f32x4_t){0.f, 0.f, 0.f, 0.f};
            }
#pragma unroll
            for (int kt = 0; kt < 4; ++kt) {
                gx[0] = mfma16(wih[0][kt], ax[kt], gx[0]);
                gx[1] = mfma16(wih[1][kt], ax[kt], gx[1]);
                gx[2] = mfma16(wih[2][kt], ax[kt], gx[2]);
                gh[0] = mfma16(whh[0][kt], ah[kt], gh[0]);
                gh[1] = mfma16(whh[1][kt], ah[kt], gh[1]);
                gh[2] = mfma16(whh[2][kt], ah[kt], gh[2]);
            }
#pragma unroll
            for (int i = 0; i < 4; ++i) {
                float rr = sigm(gx[0][i] + gh[0][i] + br[i]);
                float zz = sigm(gx[1][i] + gh[1][i] + bz[i]);
                float nn = tanh2((gx[2][i] + bin_[i]) + rr * (gh[2][i] + bhn[i]));
                h[i] = nn + zz * (h[i] - nn);
            }
            uint2 pk = pack4(h[0], h[1], h[2], h[3]);
            *(uint2*)&zbuf[p ^ 1][l15][fbase] = pk;
            stg8(h1Traj + ((size_t)t * 1024 + rbase + l15) * CTOT + fbase, pk);
            LGKM_BAR();          // LDS handoff only; h1 store drains next iter
            p ^= 1;
        }
        asm volatile("s_waitcnt vmcnt(0)" ::: "memory");
        __syncthreads();
        if (tid == 0)
            __hip_atomic_store(&h1flag[c * 128 + (TPTS - 1)], H1MAGIC(TPTS - 1),
                               __ATOMIC_RELAXED, __HIP_MEMORY_SCOPE_AGENT);
        return;
    }

    // role 2: GRU1 (no global stores in loop) + MLP head
#pragma unroll 1
    for (int t = 0; t < TPTS; ++t) {
        waitflag(&sflag[c * 128 + t], H1MAGIC(t));
        const unsigned short* xp = src + ((size_t)t * 1024 + rbase + l15) * CTOT;
        bf16x8_t ax[4], ah[4];
#pragma unroll
        for (int kt = 0; kt < 4; ++kt) {
            ax[kt] = ldfragG(xp + kt * 32 + quad * 8);
            ah[kt] = ldfrag(&zbuf[p][l15][kt * 32 + quad * 8]);
        }
        f32x4_t gx[3], gh[3];
#pragma unroll
        for (int g = 0; g < 3; ++g) {
            gx[g] = (f32x4_t){0.f, 0.f, 0.f, 0.f};
            gh[g] = (f32x4_t){0.f, 0.f, 0.f, 0.f};
        }
#pragma unroll
        for (int kt = 0; kt < 4; ++kt) {
            gx[0] = mfma16(wih[0][kt], ax[kt], gx[0]);
            gx[1] = mfma16(wih[1][kt], ax[kt], gx[1]);
            gx[2] = mfma16(wih[2][kt], ax[kt], gx[2]);
            gh[0] = mfma16(whh[0][kt], ah[kt], gh[0]);
            gh[1] = mfma16(whh[1][kt], ah[kt], gh[1]);
            gh[2] = mfma16(whh[2][kt], ah[kt], gh[2]);
        }
#pragma unroll
        for (int i = 0; i < 4; ++i) {
            float rr = sigm(gx[0][i] + gh[0][i] + br[i]);
            float zz = sigm(gx[1][i] + gh[1][i] + bz[i]);
            float nn = tanh2((gx[2][i] + bin_[i]) + rr * (gh[2][i] + bhn[i]));
            h[i] = nn + zz * (h[i] - nn);
        }
        *(uint2*)&zbuf[p ^ 1][l15][fbase] = pack4(h[0], h[1], h[2], h[3]);
        LGKM_BAR();
        p ^= 1;
    }

    // ==================== MLP head (role 2) ===================================
    if (wv < 4) {
        bf16x8_t wf[4], hf[4];
#pragma unroll
        for (int kt = 0; kt < 4; ++kt) {
            wf[kt] = ldfragW(W1v + (size_t)(wv * 16 + l15) * CTOT + kt * 32 + quad * 8);
            hf[kt] = ldfrag(&zbuf[p][l15][kt * 32 + quad * 8]);
        }
        f32x4_t acc = {0.f, 0.f, 0.f, 0.f};
#pragma unroll
        for (int kt = 0; kt < 4; ++kt) acc = mfma16(wf[kt], hf[kt], acc);
        float4 bb = *(const float4*)(b1v + wv * 16 + quad * 4);
        const float* bbp = (const float*)&bb;
        float gl[4];
#pragma unroll
        for (int i = 0; i < 4; ++i) {
            float x = acc[i] + bbp[i];
            gl[i] = 0.5f * x * (1.0f + erff(x * 0.70710678118654752f));
        }
        *(uint2*)&hidbuf[l15][wv * 16 + quad * 4] = pack4(gl[0], gl[1], gl[2], gl[3]);
    }
    __syncthreads();

    bf16x8_t ahid[2];
#pragma unroll
    for (int kt = 0; kt < 2; ++kt)
        ahid[kt] = ldfrag(&hidbuf[l15][kt * 32 + quad * 8]);
#pragma unroll 1
    for (int j = 0; j < 24; ++j) {
        int mt2 = wv * 24 + j;
        bf16x8_t wf0 = ldfragW(W2v + (size_t)(mt2 * 16 + l15) * 64 + quad * 8);
        bf16x8_t wf1 = ldfragW(W2v + (size_t)(mt2 * 16 + l15) * 64 + 32 + quad * 8);
        float4 bv = *(const float4*)(b2v + mt2 * 16 + quad * 4);
        const float* bvp = (const float*)&bv;
        f32x4_t acc = {0.f, 0.f, 0.f, 0.f};
        acc = mfma16(wf0, ahid[0], acc);
        acc = mfma16(wf1, ahid[1], acc);
        float4 o;
        o.x = acc[0] + bvp[0]; o.y = acc[1] + bvp[1];
        o.z = acc[2] + bvp[2]; o.w = acc[3] + bvp[3];
        *(float4*)(outp + (size_t)(rbase + l15) * 3072 + mt2 * 16 + quad * 4) = o;
    }
#undef YMAGIC
#undef H1MAGIC
}

extern "C" void kernel_launch(void* const* d_in, const int* in_sizes, int n_in,
                              void* d_out, int out_size, void* d_ws, size_t ws_size,
                              hipStream_t stream) {
    // setup_inputs order: 0:x(unused) 1:yl 2:yh 3:W_ode 4:b_ode 5:W_ih0 6:W_hh0
    // 7:b_ih0 8:b_hh0 9:W_ih1 10:W_hh1 11:b_ih1 12:b_hh1 13:W1 14:b1 15:W2 16:b2
    const float* yl   = (const float*)d_in[1];
    const float* yh   = (const float*)d_in[2];
    const float* Wode = (const float*)d_in[3];
    const float* bode = (const float*)d_in[4];
    const float* Wih0 = (const float*)d_in[5];
    const float* Whh0 = (const float*)d_in[6];
    const float* bih0 = (const float*)d_in[7];
    const float* bhh0 = (const float*)d_in[8];
    const float* Wih1 = (const float*)d_in[9];
    const float* Whh1 = (const float*)d_in[10];
    const float* bih1 = (const float*)d_in[11];
    const float* bhh1 = (const float*)d_in[12];
    const float* W1v  = (const float*)d_in[13];
    const float* b1v  = (const float*)d_in[14];
    const float* W2v  = (const float*)d_in[15];
    const float* b2v  = (const float*)d_in[16];

    ode_forecaster<<<dim3(192), dim3(512), 0, stream>>>(
        yl, yh, Wode, bode, Wih0, Whh0, bih0, bhh0,
        Wih1, Whh1, bih1, bhh1, W1v, b1v, W2v, b2v,
        (float*)d_out, (char*)d_ws);
}

// Round 12
// 712.272 us; speedup vs baseline: 1.0783x; 1.0783x over previous
//
#include <hip/hip_runtime.h>
#include <hip/hip_bf16.h>
#include <math.h>

#define TPTS 96
#define CTOT 128
#define LDP 134   // LDS row pitch u16: <=2-way banks (verified R4: conflicts ~0)

typedef __bf16 bf16x8_t __attribute__((ext_vector_type(8)));
typedef float f32x4_t __attribute__((ext_vector_type(4)));
typedef unsigned short us8_t __attribute__((ext_vector_type(8)));

__device__ __forceinline__ unsigned short f2b(float f) {
    union { float f; unsigned int i; } v; v.f = f;
    unsigned int r = v.i + 0x7fffu + ((v.i >> 16) & 1u);
    return (unsigned short)(r >> 16);
}
// HW packed bf16 convert (RNE, bit-identical to f2b for finite inputs):
// 1 instr replaces ~11 of manual bit-twiddling. (R6)
__device__ __forceinline__ unsigned int packbf2(float a, float b) {
    unsigned int r;
    asm("v_cvt_pk_bf16_f32 %0, %1, %2" : "=v"(r) : "v"(a), "v"(b));
    return r;
}
__device__ __forceinline__ uint2 pack4(float v0, float v1, float v2, float v3) {
    uint2 w; w.x = packbf2(v0, v1); w.y = packbf2(v2, v3); return w;
}
__device__ __forceinline__ f32x4_t mfma16(bf16x8_t a, bf16x8_t b, f32x4_t c) {
    return __builtin_amdgcn_mfma_f32_16x16x32_bf16(a, b, c, 0, 0, 0);
}
__device__ __forceinline__ bf16x8_t ldfrag(const unsigned short* p) {
    us8_t v = *(const us8_t*)p;
    return __builtin_bit_cast(bf16x8_t, v);
}
// Cross-XCD coherent fragment load: relaxed agent atomics -> plain
// global_load_dwordx2 sc0/sc1 (bypass stale L1/L2, served from LLC).
__device__ __forceinline__ bf16x8_t ldfragG(const unsigned short* p) {
    union { unsigned long long q[2]; us8_t v; } u;
    u.q[0] = __hip_atomic_load((const unsigned long long*)p,
                               __ATOMIC_RELAXED, __HIP_MEMORY_SCOPE_AGENT);
    u.q[1] = __hip_atomic_load((const unsigned long long*)(p + 4),
                               __ATOMIC_RELAXED, __HIP_MEMORY_SCOPE_AGENT);
    return __builtin_bit_cast(bf16x8_t, u.v);
}
// Cross-XCD coherent 8B store: write-through to LLC (chip coherence point).
__device__ __forceinline__ void stg8(unsigned short* p, uint2 pk) {
    unsigned long long q = ((unsigned long long)pk.y << 32) | (unsigned long long)pk.x;
    __hip_atomic_store((unsigned long long*)p, q,
                       __ATOMIC_RELAXED, __HIP_MEMORY_SCOPE_AGENT);
}
__device__ __forceinline__ bf16x8_t ldfragW(const float* p) {
    float4 a = *(const float4*)p;
    float4 b = *(const float4*)(p + 4);
    bf16x8_t r;
    r[0] = __builtin_bit_cast(__bf16, f2b(a.x)); r[1] = __builtin_bit_cast(__bf16, f2b(a.y));
    r[2] = __builtin_bit_cast(__bf16, f2b(a.z)); r[3] = __builtin_bit_cast(__bf16, f2b(a.w));
    r[4] = __builtin_bit_cast(__bf16, f2b(b.x)); r[5] = __builtin_bit_cast(__bf16, f2b(b.y));
    r[6] = __builtin_bit_cast(__bf16, f2b(b.z)); r[7] = __builtin_bit_cast(__bf16, f2b(b.w));
    return r;
}
__device__ __forceinline__ float tanh2(float x) {   // finite inputs only
    float e = __expf(x + x);
    return 1.f - __fdividef(2.f, e + 1.f);
}
#define TWO_LOG2E 2.8853900817779268f
__device__ __forceinline__ float sigm(float x) {
    return __fdividef(1.f, 1.f + __expf(-x));
}

// Raw barrier: LDS-drain only. __syncthreads() would also s_waitcnt vmcnt(0),
// putting the ~700-900cy LLC store-ack on the serial path; our global stores
// instead drain lazily at an explicit vmcnt(0) placed 1-2 stages later, where
// the ack has long arrived. The asm "memory" clobber is the compiler fence.
#define LGKM_BAR() do {                                         \
        asm volatile("s_waitcnt lgkmcnt(0)" ::: "memory");      \
        __builtin_amdgcn_s_barrier();                           \
    } while (0)

// role-2 consumer poll (role-1 has the release/spin inlined for flag deferral)
__device__ __forceinline__ void waitflag(unsigned int* f, unsigned int want) {
    if (threadIdx.x == 0) {
        int guard = 0;
        while (__hip_atomic_load(f, __ATOMIC_RELAXED, __HIP_MEMORY_SCOPE_AGENT) != want) {
            __builtin_amdgcn_s_sleep(1);
            if (++guard > (1 << 22)) break;   // hang-proof: degrade, don't wedge
        }
    }
    __syncthreads();
}
__device__ __forceinline__ void setflag(unsigned int* f, unsigned int val) {
    if (threadIdx.x == 0) {
        asm volatile("s_waitcnt vmcnt(0)" ::: "memory");  // data globally visible first
        __hip_atomic_store(f, val, __ATOMIC_RELAXED, __HIP_MEMORY_SCOPE_AGENT);
    }
}

// R16 = banked R2 structure + producer critical-CHAIN shave (exp2-form tanh,
// fmaf tail, fresh-k enters combines via single fmaf onto precomputed prefix).
// Theory: stage wall is chain-bound at a pinned low effective clock (fits
// R1/R2 null on issue cuts, R7 linear scaling, R8 ballast null); chain is
// lgkm-wait->MFMA->add->tanh->combine->pack->write->barrier; this removes ~3
// dependent ops/stage. 192 blocks x 512 thr: role = blockIdx>>6
// (0:ODE producer, 1:GRU0, 2:GRU1+head). Each role-c block owns rows
// [16c,16c+16). ODE critical path = 570 stages.
__global__ void __launch_bounds__(512, 2)
ode_forecaster(const float* __restrict__ yl,
               const float* __restrict__ yh,
               const float* __restrict__ Wode,
               const float* __restrict__ bode,
               const float* __restrict__ Wih0,
               const float* __restrict__ Whh0,
               const float* __restrict__ bih0,
               const float* __restrict__ bhh0,
               const float* __restrict__ Wih1,
               const float* __restrict__ Whh1,
               const float* __restrict__ bih1,
               const float* __restrict__ bhh1,
               const float* __restrict__ W1v,
               const float* __restrict__ b1v,
               const float* __restrict__ W2v,
               const float* __restrict__ b2v,
               float* __restrict__ outp,
               char* __restrict__ wsb)
{
    const int role = blockIdx.x >> 6;
    const int c    = blockIdx.x & 63;
    const int tid  = threadIdx.x, lane = tid & 63, wv = tid >> 6;
    const int l15  = lane & 15, quad = lane >> 4;
    const int fbase = wv * 16 + quad * 4;
    const int rbase = c * 16;

    __shared__ __align__(16) unsigned short zbuf[2][16][LDP];
    __shared__ __align__(16) unsigned short hidbuf[16][72];

    unsigned short* yTraj  = (unsigned short*)(wsb);
    unsigned short* h1Traj = (unsigned short*)(wsb + 0x2000000);
    unsigned int*   yflag  = (unsigned int*)(wsb + 0x4000000);
    unsigned int*   h1flag = (unsigned int*)(wsb + 0x4010000);
#define YMAGIC(t)  (0x5E000000u + (unsigned)(t))
#define H1MAGIC(t) (0x6E000000u + (unsigned)(t))

    if (role == 0) {
        // ================= ODE producer (the serial critical path) ===========
        bf16x8_t wode[4];
#pragma unroll
        for (int kt = 0; kt < 4; ++kt)
            wode[kt] = ldfragW(Wode + (wv * 16 + l15) * CTOT + kt * 32 + quad * 8);
        float bo2[4];   // 2*bias*log2e: exp2-form argument via one FMA (chain -1)
        {
            float4 b4 = *(const float4*)(bode + fbase);
            bo2[0] = b4.x * TWO_LOG2E; bo2[1] = b4.y * TWO_LOG2E;
            bo2[2] = b4.z * TWO_LOG2E; bo2[3] = b4.w * TWO_LOG2E;
        }
        float y[4];
        {
            int row = rbase + l15;
#pragma unroll
            for (int i = 0; i < 4; ++i) {
                int f = fbase + i;
                y[i] = (f < 32) ? yl[row * 32 + f] : yh[row * 96 + (f - 32)];
            }
            uint2 pk = pack4(y[0], y[1], y[2], y[3]);
            *(uint2*)&zbuf[0][l15][fbase] = pk;
            stg8(yTraj + ((size_t)row) * CTOT + fbase, pk);
        }
        __syncthreads();                      // full drain (once, pre-loop)
        setflag(&yflag[c * 128 + 0], YMAGIC(0));

        // dt-folded Dormand-Prince coefficients
        const float dt = 1.0f / 95.0f;
        const float d10 = dt * 0.2f;
        const float d20 = dt * (3.f/40.f),  d21 = dt * (9.f/40.f);
        const float d30 = dt * (44.f/45.f), d31 = dt * (-56.f/15.f), d32 = dt * (32.f/9.f);
        const float d40 = dt * (19372.f/6561.f), d41 = dt * (-25360.f/2187.f),
                    d42 = dt * (64448.f/6561.f), d43 = dt * (-212.f/729.f);
        const float d50 = dt * (9017.f/3168.f), d51 = dt * (-355.f/33.f),
                    d52 = dt * (46732.f/5247.f), d53 = dt * (49.f/176.f),
                    d54 = dt * (-5103.f/18656.f);
        const float e0 = dt * (35.f/384.f), e2 = dt * (500.f/1113.f), e3 = dt * (125.f/192.f),
                    e4 = dt * (-2187.f/6784.f), e5 = dt * (11.f/84.f);

        int p = 0;
        float kr[6][4];
#pragma unroll 1
        for (int t = 0; t < 95; ++t) {
#pragma unroll
            for (int s = 0; s < 6; ++s) {
                bf16x8_t bf[4];
#pragma unroll
                for (int kt = 0; kt < 4; ++kt)
                    bf[kt] = ldfrag(&zbuf[p][l15][kt * 32 + quad * 8]);
                // 4 independent accumulators + tree add: 1-deep MFMA chain
                const f32x4_t zz = {0.f, 0.f, 0.f, 0.f};
                f32x4_t a0 = mfma16(wode[0], bf[0], zz);
                f32x4_t a1 = mfma16(wode[1], bf[1], zz);
                f32x4_t a2 = mfma16(wode[2], bf[2], zz);
                f32x4_t a3 = mfma16(wode[3], bf[3], zz);
                f32x4_t acc = (a0 + a1) + (a2 + a3);
                // tanh chain: fmaf -> exp2 -> add -> rcp -> fmaf  (3 ops shorter
                // than __expf/div/sub form; matches R3-R7 producers' numerics)
#pragma unroll
                for (int i = 0; i < 4; ++i) {
                    float e = __builtin_amdgcn_exp2f(fmaf(acc[i], TWO_LOG2E, bo2[i]));
                    float r = __builtin_amdgcn_rcpf(e + 1.f);
                    kr[s][i] = fmaf(-2.f, r, 1.f);
                }

                if (s < 5) {
                    float z[4];
#pragma unroll
                    for (int i = 0; i < 4; ++i) {
                        // prefix uses only already-known kr[<s] and y -> the
                        // compiler schedules it under the exp latency; fresh k
                        // enters through exactly ONE fmaf (chain depth 1).
                        float zv;
                        if (s == 0)      zv = fmaf(d10, kr[0][i], y[i]);
                        else if (s == 1) zv = fmaf(d21, kr[1][i],
                                               fmaf(d20, kr[0][i], y[i]));
                        else if (s == 2) zv = fmaf(d32, kr[2][i],
                                               fmaf(d31, kr[1][i],
                                               fmaf(d30, kr[0][i], y[i])));
                        else if (s == 3) zv = fmaf(d43, kr[3][i],
                                               fmaf(d42, kr[2][i],
                                               fmaf(d41, kr[1][i],
                                               fmaf(d40, kr[0][i], y[i]))));
                        else             zv = fmaf(d54, kr[4][i],
                                               fmaf(d53, kr[3][i],
                                               fmaf(d52, kr[2][i],
                                               fmaf(d51, kr[1][i],
                                               fmaf(d50, kr[0][i], y[i])))));
                        z[i] = zv;
                    }
                    *(uint2*)&zbuf[p ^ 1][l15][fbase] = pack4(z[0], z[1], z[2], z[3]);
                } else {
#pragma unroll
                    for (int i = 0; i < 4; ++i)
                        y[i] = fmaf(e5, kr[5][i],
                               fmaf(e4, kr[4][i],
                               fmaf(e3, kr[3][i],
                               fmaf(e2, kr[2][i],
                               fmaf(e0, kr[0][i], y[i])))));
                    uint2 pk = pack4(y[0], y[1], y[2], y[3]);
                    *(uint2*)&zbuf[p ^ 1][l15][fbase] = pk;
                    // issue the trajectory store; it drains (vmcnt) 2 stages
                    // later at s==1 of t+1, where the LLC ack has long landed.
                    stg8(yTraj + ((size_t)(t + 1) * 1024 + rbase + l15) * CTOT + fbase, pk);
                }
                if (s == 1)   // deferred-drain point for the store issued at t-1,s5
                    asm volatile("s_waitcnt vmcnt(0)" ::: "memory");
                LGKM_BAR();
                if (s == 1 && t > 0 && tid == 0)
                    __hip_atomic_store(&yflag[c * 128 + t], YMAGIC(t),
                                       __ATOMIC_RELAXED, __HIP_MEMORY_SCOPE_AGENT);
                p ^= 1;
            }
        }
        // final flag (y[95] stored at t=94,s5)
        asm volatile("s_waitcnt vmcnt(0)" ::: "memory");
        __builtin_amdgcn_s_barrier();
        if (tid == 0)
            __hip_atomic_store(&yflag[c * 128 + 95], YMAGIC(95),
                               __ATOMIC_RELAXED, __HIP_MEMORY_SCOPE_AGENT);
        return;
    }

    // ==================== GRU consumer roles ==================================
    const float* Wih = (role == 1) ? Wih0 : Wih1;
    const float* Whh = (role == 1) ? Whh0 : Whh1;
    const float* bih = (role == 1) ? bih0 : bih1;
    const float* bhh = (role == 1) ? bhh0 : bhh1;
    const unsigned short* src = (role == 1) ? yTraj : h1Traj;
    unsigned int* sflag = (role == 1) ? yflag : h1flag;

    bf16x8_t wih[3][4], whh[3][4];
#pragma unroll
    for (int g = 0; g < 3; ++g)
#pragma unroll
        for (int kt = 0; kt < 4; ++kt) {
            wih[g][kt] = ldfragW(Wih + (size_t)(g * 128 + wv * 16 + l15) * CTOT + kt * 32 + quad * 8);
            whh[g][kt] = ldfragW(Whh + (size_t)(g * 128 + wv * 16 + l15) * CTOT + kt * 32 + quad * 8);
        }
    float br[4], bz[4], bin_[4], bhn[4];
    {
        float4 a0 = *(const float4*)(bih + 0 * 128 + fbase);
        float4 b0 = *(const float4*)(bhh + 0 * 128 + fbase);
        float4 a1 = *(const float4*)(bih + 1 * 128 + fbase);
        float4 b1 = *(const float4*)(bhh + 1 * 128 + fbase);
        float4 a2 = *(const float4*)(bih + 2 * 128 + fbase);
        float4 b2 = *(const float4*)(bhh + 2 * 128 + fbase);
        br[0] = a0.x + b0.x; br[1] = a0.y + b0.y; br[2] = a0.z + b0.z; br[3] = a0.w + b0.w;
        bz[0] = a1.x + b1.x; bz[1] = a1.y + b1.y; bz[2] = a1.z + b1.z; bz[3] = a1.w + b1.w;
        bin_[0] = a2.x; bin_[1] = a2.y; bin_[2] = a2.z; bin_[3] = a2.w;
        bhn[0] = b2.x; bhn[1] = b2.y; bhn[2] = b2.z; bhn[3] = b2.w;
    }

    float h[4] = {0.f, 0.f, 0.f, 0.f};
    *(uint2*)&zbuf[0][l15][fbase] = pack4(0.f, 0.f, 0.f, 0.f);
    int p = 0;
    __syncthreads();

    if (role == 1) {
        // GRU0: deferred h1-flag release — t-1's store drains during t's flag
        // wait (dead time), so no vmcnt(0) ever sits on the compute path.
#pragma unroll 1
        for (int t = 0; t < TPTS; ++t) {
            asm volatile("s_waitcnt vmcnt(0)" ::: "memory");   // drain t-1 store (free by now)
            __builtin_amdgcn_s_barrier();                      // all waves drained
            if (tid == 0) {
                if (t > 0)
                    __hip_atomic_store(&h1flag[c * 128 + (t - 1)], H1MAGIC(t - 1),
                                       __ATOMIC_RELAXED, __HIP_MEMORY_SCOPE_AGENT);
                int guard = 0;
                while (__hip_atomic_load(&yflag[c * 128 + t],
                                         __ATOMIC_RELAXED, __HIP_MEMORY_SCOPE_AGENT) != YMAGIC(t)) {
                    __builtin_amdgcn_s_sleep(1);
                    if (++guard > (1 << 22)) break;
                }
            }
            __syncthreads();
            const unsigned short* xp = src + ((size_t)t * 1024 + rbase + l15) * CTOT;
            bf16x8_t ax[4], ah[4];
#pragma unroll
            for (int kt = 0; kt < 4; ++kt) {
                ax[kt] = ldfragG(xp + kt * 32 + quad * 8);
                ah[kt] = ldfrag(&zbuf[p][l15][kt * 32 + quad * 8]);
            }
            f32x4_t gx[3], gh[3];
#pragma unroll
            for (int g = 0; g < 3; ++g) {
                gx[g] = (f32x4_t){0.f, 0.f, 0.f, 0.f};
                gh[g] = (f32x4_t){0.f, 0.f, 0.f, 0.f};
            }
#pragma unroll
            for (int kt = 0; kt < 4; ++kt) {
                gx[0] = mfma16(wih[0][kt], ax[kt], gx[0]);
                gx[1] = mfma16(wih[1][kt], ax[kt], gx[1]);
                gx[2] = mfma16(wih[2][kt], ax[kt], gx[2]);
                gh[0] = mfma16(whh[0][kt], ah[kt], gh[0]);
                gh[1] = mfma16(whh[1][kt], ah[kt], gh[1]);
                gh[2] = mfma16(whh[2][kt], ah[kt], gh[2]);
            }
#pragma unroll
            for (int i = 0; i < 4; ++i) {
                float rr = sigm(gx[0][i] + gh[0][i] + br[i]);
                float zz = sigm(gx[1][i] + gh[1][i] + bz[i]);
                float nn = tanh2((gx[2][i] + bin_[i]) + rr * (gh[2][i] + bhn[i]));
                h[i] = nn + zz * (h[i] - nn);
            }
            uint2 pk = pack4(h[0], h[1], h[2], h[3]);
            *(uint2*)&zbuf[p ^ 1][l15][fbase] = pk;
            stg8(h1Traj + ((size_t)t * 1024 + rbase + l15) * CTOT + fbase, pk);
            LGKM_BAR();          // LDS handoff only; h1 store drains next iter
            p ^= 1;
        }
        asm volatile("s_waitcnt vmcnt(0)" ::: "memory");
        __syncthreads();
        if (tid == 0)
            __hip_atomic_store(&h1flag[c * 128 + (TPTS - 1)], H1MAGIC(TPTS - 1),
                               __ATOMIC_RELAXED, __HIP_MEMORY_SCOPE_AGENT);
        return;
    }

    // role 2: GRU1 (no global stores in loop) + MLP head
#pragma unroll 1
    for (int t = 0; t < TPTS; ++t) {
        waitflag(&sflag[c * 128 + t], H1MAGIC(t));
        const unsigned short* xp = src + ((size_t)t * 1024 + rbase + l15) * CTOT;
        bf16x8_t ax[4], ah[4];
#pragma unroll
        for (int kt = 0; kt < 4; ++kt) {
            ax[kt] = ldfragG(xp + kt * 32 + quad * 8);
            ah[kt] = ldfrag(&zbuf[p][l15][kt * 32 + quad * 8]);
        }
        f32x4_t gx[3], gh[3];
#pragma unroll
        for (int g = 0; g < 3; ++g) {
            gx[g] = (f32x4_t){0.f, 0.f, 0.f, 0.f};
            gh[g] = (f32x4_t){0.f, 0.f, 0.f, 0.f};
        }
#pragma unroll
        for (int kt = 0; kt < 4; ++kt) {
            gx[0] = mfma16(wih[0][kt], ax[kt], gx[0]);
            gx[1] = mfma16(wih[1][kt], ax[kt], gx[1]);
            gx[2] = mfma16(wih[2][kt], ax[kt], gx[2]);
            gh[0] = mfma16(whh[0][kt], ah[kt], gh[0]);
            gh[1] = mfma16(whh[1][kt], ah[kt], gh[1]);
            gh[2] = mfma16(whh[2][kt], ah[kt], gh[2]);
        }
#pragma unroll
        for (int i = 0; i < 4; ++i) {
            float rr = sigm(gx[0][i] + gh[0][i] + br[i]);
            float zz = sigm(gx[1][i] + gh[1][i] + bz[i]);
            float nn = tanh2((gx[2][i] + bin_[i]) + rr * (gh[2][i] + bhn[i]));
            h[i] = nn + zz * (h[i] - nn);
        }
        *(uint2*)&zbuf[p ^ 1][l15][fbase] = pack4(h[0], h[1], h[2], h[3]);
        LGKM_BAR();
        p ^= 1;
    }

    // ==================== MLP head (role 2) ===================================
    if (wv < 4) {
        bf16x8_t wf[4], hf[4];
#pragma unroll
        for (int kt = 0; kt < 4; ++kt) {
            wf[kt] = ldfragW(W1v + (size_t)(wv * 16 + l15) * CTOT + kt * 32 + quad * 8);
            hf[kt] = ldfrag(&zbuf[p][l15][kt * 32 + quad * 8]);
        }
        f32x4_t acc = {0.f, 0.f, 0.f, 0.f};
#pragma unroll
        for (int kt = 0; kt < 4; ++kt) acc = mfma16(wf[kt], hf[kt], acc);
        float4 bb = *(const float4*)(b1v + wv * 16 + quad * 4);
        const float* bbp = (const float*)&bb;
        float gl[4];
#pragma unroll
        for (int i = 0; i < 4; ++i) {
            float x = acc[i] + bbp[i];
            gl[i] = 0.5f * x * (1.0f + erff(x * 0.70710678118654752f));
        }
        *(uint2*)&hidbuf[l15][wv * 16 + quad * 4] = pack4(gl[0], gl[1], gl[2], gl[3]);
    }
    __syncthreads();

    bf16x8_t ahid[2];
#pragma unroll
    for (int kt = 0; kt < 2; ++kt)
        ahid[kt] = ldfrag(&hidbuf[l15][kt * 32 + quad * 8]);
#pragma unroll 1
    for (int j = 0; j < 24; ++j) {
        int mt2 = wv * 24 + j;
        bf16x8_t wf0 = ldfragW(W2v + (size_t)(mt2 * 16 + l15) * 64 + quad * 8);
        bf16x8_t wf1 = ldfragW(W2v + (size_t)(mt2 * 16 + l15) * 64 + 32 + quad * 8);
        float4 bv = *(const float4*)(b2v + mt2 * 16 + quad * 4);
        const float* bvp = (const float*)&bv;
        f32x4_t acc = {0.f, 0.f, 0.f, 0.f};
        acc = mfma16(wf0, ahid[0], acc);
        acc = mfma16(wf1, ahid[1], acc);
        float4 o;
        o.x = acc[0] + bvp[0]; o.y = acc[1] + bvp[1];
        o.z = acc[2] + bvp[2]; o.w = acc[3] + bvp[3];
        *(float4*)(outp + (size_t)(rbase + l15) * 3072 + mt2 * 16 + quad * 4) = o;
    }
#undef YMAGIC
#undef H1MAGIC
}

extern "C" void kernel_launch(void* const* d_in, const int* in_sizes, int n_in,
                              void* d_out, int out_size, void* d_ws, size_t ws_size,
                              hipStream_t stream) {
    // setup_inputs order: 0:x(unused) 1:yl 2:yh 3:W_ode 4:b_ode 5:W_ih0 6:W_hh0
    // 7:b_ih0 8:b_hh0 9:W_ih1 10:W_hh1 11:b_ih1 12:b_hh1 13:W1 14:b1 15:W2 16:b2
    const float* yl   = (const float*)d_in[1];
    const float* yh   = (const float*)d_in[2];
    const float* Wode = (const float*)d_in[3];
    const float* bode = (const float*)d_in[4];
    const float* Wih0 = (const float*)d_in[5];
    const float* Whh0 = (const float*)d_in[6];
    const float* bih0 = (const float*)d_in[7];
    const float* bhh0 = (const float*)d_in[8];
    const float* Wih1 = (const float*)d_in[9];
    const float* Whh1 = (const float*)d_in[10];
    const float* bih1 = (const float*)d_in[11];
    const float* bhh1 = (const float*)d_in[12];
    const float* W1v  = (const float*)d_in[13];
    const float* b1v  = (const float*)d_in[14];
    const float* W2v  = (const float*)d_in[15];
    const float* b2v  = (const float*)d_in[16];

    ode_forecaster<<<dim3(192), dim3(512), 0, stream>>>(
        yl, yh, Wode, bode, Wih0, Whh0, bih0, bhh0,
        Wih1, Whh1, bih1, bhh1, W1v, b1v, W2v, b2v,
        (float*)d_out, (char*)d_ws);
}

// Round 13
// 712.172 us; speedup vs baseline: 1.0785x; 1.0001x over previous
//
#include <hip/hip_runtime.h>
#include <hip/hip_bf16.h>
#include <math.h>

#define TPTS 96
#define CTOT 128
#define LDP 134   // LDS row pitch u16: <=2-way banks (verified R4: conflicts ~0)

typedef __bf16 bf16x8_t __attribute__((ext_vector_type(8)));
typedef float f32x4_t __attribute__((ext_vector_type(4)));
typedef unsigned short us8_t __attribute__((ext_vector_type(8)));

__device__ __forceinline__ unsigned short f2b(float f) {
    union { float f; unsigned int i; } v; v.f = f;
    unsigned int r = v.i + 0x7fffu + ((v.i >> 16) & 1u);
    return (unsigned short)(r >> 16);
}
// HW packed bf16 convert (RNE, bit-identical to f2b for finite inputs):
// 1 instr replaces ~11 of manual bit-twiddling. (R6)
__device__ __forceinline__ unsigned int packbf2(float a, float b) {
    unsigned int r;
    asm("v_cvt_pk_bf16_f32 %0, %1, %2" : "=v"(r) : "v"(a), "v"(b));
    return r;
}
__device__ __forceinline__ uint2 pack4(float v0, float v1, float v2, float v3) {
    uint2 w; w.x = packbf2(v0, v1); w.y = packbf2(v2, v3); return w;
}
__device__ __forceinline__ f32x4_t mfma16(bf16x8_t a, bf16x8_t b, f32x4_t c) {
    return __builtin_amdgcn_mfma_f32_16x16x32_bf16(a, b, c, 0, 0, 0);
}
__device__ __forceinline__ bf16x8_t ldfrag(const unsigned short* p) {
    us8_t v = *(const us8_t*)p;
    return __builtin_bit_cast(bf16x8_t, v);
}
// Cross-XCD coherent fragment load: relaxed agent atomics -> plain
// global_load_dwordx2 sc0/sc1 (bypass stale L1/L2, served from LLC).
__device__ __forceinline__ bf16x8_t ldfragG(const unsigned short* p) {
    union { unsigned long long q[2]; us8_t v; } u;
    u.q[0] = __hip_atomic_load((const unsigned long long*)p,
                               __ATOMIC_RELAXED, __HIP_MEMORY_SCOPE_AGENT);
    u.q[1] = __hip_atomic_load((const unsigned long long*)(p + 4),
                               __ATOMIC_RELAXED, __HIP_MEMORY_SCOPE_AGENT);
    return __builtin_bit_cast(bf16x8_t, u.v);
}
// Cross-XCD coherent 8B store: write-through to LLC (chip coherence point).
__device__ __forceinline__ void stg8(unsigned short* p, uint2 pk) {
    unsigned long long q = ((unsigned long long)pk.y << 32) | (unsigned long long)pk.x;
    __hip_atomic_store((unsigned long long*)p, q,
                       __ATOMIC_RELAXED, __HIP_MEMORY_SCOPE_AGENT);
}
__device__ __forceinline__ bf16x8_t ldfragW(const float* p) {
    float4 a = *(const float4*)p;
    float4 b = *(const float4*)(p + 4);
    bf16x8_t r;
    r[0] = __builtin_bit_cast(__bf16, f2b(a.x)); r[1] = __builtin_bit_cast(__bf16, f2b(a.y));
    r[2] = __builtin_bit_cast(__bf16, f2b(a.z)); r[3] = __builtin_bit_cast(__bf16, f2b(a.w));
    r[4] = __builtin_bit_cast(__bf16, f2b(b.x)); r[5] = __builtin_bit_cast(__bf16, f2b(b.y));
    r[6] = __builtin_bit_cast(__bf16, f2b(b.z)); r[7] = __builtin_bit_cast(__bf16, f2b(b.w));
    return r;
}
#define TWO_LOG2E 2.8853900817779268f
#define NLOG2E   -1.4426950408889634f

// Raw barrier: LDS-drain only. __syncthreads() would also s_waitcnt vmcnt(0),
// putting the ~700-900cy LLC store-ack on the serial path; our global stores
// instead drain lazily at an explicit vmcnt(0) placed 1-2 stages later, where
// the ack has long arrived. The asm "memory" clobber is the compiler fence.
#define LGKM_BAR() do {                                         \
        asm volatile("s_waitcnt lgkmcnt(0)" ::: "memory");      \
        __builtin_amdgcn_s_barrier();                           \
    } while (0)

// role-2 consumer poll (role-1 has the release/spin inlined for flag deferral)
__device__ __forceinline__ void waitflag(unsigned int* f, unsigned int want) {
    if (threadIdx.x == 0) {
        int guard = 0;
        while (__hip_atomic_load(f, __ATOMIC_RELAXED, __HIP_MEMORY_SCOPE_AGENT) != want) {
            __builtin_amdgcn_s_sleep(1);
            if (++guard > (1 << 22)) break;   // hang-proof: degrade, don't wedge
        }
    }
    __syncthreads();
}
__device__ __forceinline__ void setflag(unsigned int* f, unsigned int val) {
    if (threadIdx.x == 0) {
        asm volatile("s_waitcnt vmcnt(0)" ::: "memory");  // data globally visible first
        __hip_atomic_store(f, val, __ATOMIC_RELAXED, __HIP_MEMORY_SCOPE_AGENT);
    }
}

// R17 = R12 (banked 636us: producer chain-shaved) + CONSUMER chain shave.
// R12 confirmed the stage wall is dependency-chain-bound (~65cy per chain op);
// this round shortens the GRU cells' chains: (1) gx accumulation seeded with
// pre-computed gh accumulators via the free MFMA C-operand (r,z gates) -> chain
// 4 MFMA -> 2 MFMA + 1 add; (2) exp2-form sigmoid/tanh with biases pre-folded
// (brl/bzl = -(bi+bh)*log2e; bin2/bhn2 = b*2log2e); (3) n-gate argument as one
// fmaf(rr, t1s, t0s) with t1s precomputed off-chain; (4) h = fmaf(zz,h-nn,nn).
// Producer + all sync structure byte-identical to R12.
__global__ void __launch_bounds__(512, 2)
ode_forecaster(const float* __restrict__ yl,
               const float* __restrict__ yh,
               const float* __restrict__ Wode,
               const float* __restrict__ bode,
               const float* __restrict__ Wih0,
               const float* __restrict__ Whh0,
               const float* __restrict__ bih0,
               const float* __restrict__ bhh0,
               const float* __restrict__ Wih1,
               const float* __restrict__ Whh1,
               const float* __restrict__ bih1,
               const float* __restrict__ bhh1,
               const float* __restrict__ W1v,
               const float* __restrict__ b1v,
               const float* __restrict__ W2v,
               const float* __restrict__ b2v,
               float* __restrict__ outp,
               char* __restrict__ wsb)
{
    const int role = blockIdx.x >> 6;
    const int c    = blockIdx.x & 63;
    const int tid  = threadIdx.x, lane = tid & 63, wv = tid >> 6;
    const int l15  = lane & 15, quad = lane >> 4;
    const int fbase = wv * 16 + quad * 4;
    const int rbase = c * 16;

    __shared__ __align__(16) unsigned short zbuf[2][16][LDP];
    __shared__ __align__(16) unsigned short hidbuf[16][72];

    unsigned short* yTraj  = (unsigned short*)(wsb);
    unsigned short* h1Traj = (unsigned short*)(wsb + 0x2000000);
    unsigned int*   yflag  = (unsigned int*)(wsb + 0x4000000);
    unsigned int*   h1flag = (unsigned int*)(wsb + 0x4010000);
#define YMAGIC(t)  (0x5E000000u + (unsigned)(t))
#define H1MAGIC(t) (0x6E000000u + (unsigned)(t))

    if (role == 0) {
        // ================= ODE producer (R12 verbatim) =======================
        bf16x8_t wode[4];
#pragma unroll
        for (int kt = 0; kt < 4; ++kt)
            wode[kt] = ldfragW(Wode + (wv * 16 + l15) * CTOT + kt * 32 + quad * 8);
        float bo2[4];   // 2*bias*log2e: exp2-form argument via one FMA
        {
            float4 b4 = *(const float4*)(bode + fbase);
            bo2[0] = b4.x * TWO_LOG2E; bo2[1] = b4.y * TWO_LOG2E;
            bo2[2] = b4.z * TWO_LOG2E; bo2[3] = b4.w * TWO_LOG2E;
        }
        float y[4];
        {
            int row = rbase + l15;
#pragma unroll
            for (int i = 0; i < 4; ++i) {
                int f = fbase + i;
                y[i] = (f < 32) ? yl[row * 32 + f] : yh[row * 96 + (f - 32)];
            }
            uint2 pk = pack4(y[0], y[1], y[2], y[3]);
            *(uint2*)&zbuf[0][l15][fbase] = pk;
            stg8(yTraj + ((size_t)row) * CTOT + fbase, pk);
        }
        __syncthreads();                      // full drain (once, pre-loop)
        setflag(&yflag[c * 128 + 0], YMAGIC(0));

        // dt-folded Dormand-Prince coefficients
        const float dt = 1.0f / 95.0f;
        const float d10 = dt * 0.2f;
        const float d20 = dt * (3.f/40.f),  d21 = dt * (9.f/40.f);
        const float d30 = dt * (44.f/45.f), d31 = dt * (-56.f/15.f), d32 = dt * (32.f/9.f);
        const float d40 = dt * (19372.f/6561.f), d41 = dt * (-25360.f/2187.f),
                    d42 = dt * (64448.f/6561.f), d43 = dt * (-212.f/729.f);
        const float d50 = dt * (9017.f/3168.f), d51 = dt * (-355.f/33.f),
                    d52 = dt * (46732.f/5247.f), d53 = dt * (49.f/176.f),
                    d54 = dt * (-5103.f/18656.f);
        const float e0 = dt * (35.f/384.f), e2 = dt * (500.f/1113.f), e3 = dt * (125.f/192.f),
                    e4 = dt * (-2187.f/6784.f), e5 = dt * (11.f/84.f);

        int p = 0;
        float kr[6][4];
#pragma unroll 1
        for (int t = 0; t < 95; ++t) {
#pragma unroll
            for (int s = 0; s < 6; ++s) {
                bf16x8_t bf[4];
#pragma unroll
                for (int kt = 0; kt < 4; ++kt)
                    bf[kt] = ldfrag(&zbuf[p][l15][kt * 32 + quad * 8]);
                // 4 independent accumulators + tree add: 1-deep MFMA chain
                const f32x4_t zz = {0.f, 0.f, 0.f, 0.f};
                f32x4_t a0 = mfma16(wode[0], bf[0], zz);
                f32x4_t a1 = mfma16(wode[1], bf[1], zz);
                f32x4_t a2 = mfma16(wode[2], bf[2], zz);
                f32x4_t a3 = mfma16(wode[3], bf[3], zz);
                f32x4_t acc = (a0 + a1) + (a2 + a3);
                // tanh chain: fmaf -> exp2 -> add -> rcp -> fmaf
#pragma unroll
                for (int i = 0; i < 4; ++i) {
                    float e = __builtin_amdgcn_exp2f(fmaf(acc[i], TWO_LOG2E, bo2[i]));
                    float r = __builtin_amdgcn_rcpf(e + 1.f);
                    kr[s][i] = fmaf(-2.f, r, 1.f);
                }

                if (s < 5) {
                    float z[4];
#pragma unroll
                    for (int i = 0; i < 4; ++i) {
                        // prefix from known kr[<s] schedules under exp latency;
                        // fresh k enters through exactly ONE fmaf.
                        float zv;
                        if (s == 0)      zv = fmaf(d10, kr[0][i], y[i]);
                        else if (s == 1) zv = fmaf(d21, kr[1][i],
                                               fmaf(d20, kr[0][i], y[i]));
                        else if (s == 2) zv = fmaf(d32, kr[2][i],
                                               fmaf(d31, kr[1][i],
                                               fmaf(d30, kr[0][i], y[i])));
                        else if (s == 3) zv = fmaf(d43, kr[3][i],
                                               fmaf(d42, kr[2][i],
                                               fmaf(d41, kr[1][i],
                                               fmaf(d40, kr[0][i], y[i]))));
                        else             zv = fmaf(d54, kr[4][i],
                                               fmaf(d53, kr[3][i],
                                               fmaf(d52, kr[2][i],
                                               fmaf(d51, kr[1][i],
                                               fmaf(d50, kr[0][i], y[i])))));
                        z[i] = zv;
                    }
                    *(uint2*)&zbuf[p ^ 1][l15][fbase] = pack4(z[0], z[1], z[2], z[3]);
                } else {
#pragma unroll
                    for (int i = 0; i < 4; ++i)
                        y[i] = fmaf(e5, kr[5][i],
                               fmaf(e4, kr[4][i],
                               fmaf(e3, kr[3][i],
                               fmaf(e2, kr[2][i],
                               fmaf(e0, kr[0][i], y[i])))));
                    uint2 pk = pack4(y[0], y[1], y[2], y[3]);
                    *(uint2*)&zbuf[p ^ 1][l15][fbase] = pk;
                    stg8(yTraj + ((size_t)(t + 1) * 1024 + rbase + l15) * CTOT + fbase, pk);
                }
                if (s == 1)   // deferred-drain point for the store issued at t-1,s5
                    asm volatile("s_waitcnt vmcnt(0)" ::: "memory");
                LGKM_BAR();
                if (s == 1 && t > 0 && tid == 0)
                    __hip_atomic_store(&yflag[c * 128 + t], YMAGIC(t),
                                       __ATOMIC_RELAXED, __HIP_MEMORY_SCOPE_AGENT);
                p ^= 1;
            }
        }
        // final flag (y[95] stored at t=94,s5)
        asm volatile("s_waitcnt vmcnt(0)" ::: "memory");
        __builtin_amdgcn_s_barrier();
        if (tid == 0)
            __hip_atomic_store(&yflag[c * 128 + 95], YMAGIC(95),
                               __ATOMIC_RELAXED, __HIP_MEMORY_SCOPE_AGENT);
        return;
    }

    // ==================== GRU consumer roles ==================================
    const float* Wih = (role == 1) ? Wih0 : Wih1;
    const float* Whh = (role == 1) ? Whh0 : Whh1;
    const float* bih = (role == 1) ? bih0 : bih1;
    const float* bhh = (role == 1) ? bhh0 : bhh1;
    const unsigned short* src = (role == 1) ? yTraj : h1Traj;
    unsigned int* sflag = (role == 1) ? yflag : h1flag;

    bf16x8_t wih[3][4], whh[3][4];
#pragma unroll
    for (int g = 0; g < 3; ++g)
#pragma unroll
        for (int kt = 0; kt < 4; ++kt) {
            wih[g][kt] = ldfragW(Wih + (size_t)(g * 128 + wv * 16 + l15) * CTOT + kt * 32 + quad * 8);
            whh[g][kt] = ldfragW(Whh + (size_t)(g * 128 + wv * 16 + l15) * CTOT + kt * 32 + quad * 8);
        }
    // pre-folded biases for exp2-form activations (chain -1 op each):
    // brl/bzl = -(bih+bhh)*log2e ; bin2 = bih_n*2log2e ; bhn2 = bhh_n*2log2e
    float brl[4], bzl[4], bin2[4], bhn2[4];
    {
        float4 a0 = *(const float4*)(bih + 0 * 128 + fbase);
        float4 b0 = *(const float4*)(bhh + 0 * 128 + fbase);
        float4 a1 = *(const float4*)(bih + 1 * 128 + fbase);
        float4 b1 = *(const float4*)(bhh + 1 * 128 + fbase);
        float4 a2 = *(const float4*)(bih + 2 * 128 + fbase);
        float4 b2 = *(const float4*)(bhh + 2 * 128 + fbase);
        brl[0] = (a0.x + b0.x) * NLOG2E; brl[1] = (a0.y + b0.y) * NLOG2E;
        brl[2] = (a0.z + b0.z) * NLOG2E; brl[3] = (a0.w + b0.w) * NLOG2E;
        bzl[0] = (a1.x + b1.x) * NLOG2E; bzl[1] = (a1.y + b1.y) * NLOG2E;
        bzl[2] = (a1.z + b1.z) * NLOG2E; bzl[3] = (a1.w + b1.w) * NLOG2E;
        bin2[0] = a2.x * TWO_LOG2E; bin2[1] = a2.y * TWO_LOG2E;
        bin2[2] = a2.z * TWO_LOG2E; bin2[3] = a2.w * TWO_LOG2E;
        bhn2[0] = b2.x * TWO_LOG2E; bhn2[1] = b2.y * TWO_LOG2E;
        bhn2[2] = b2.z * TWO_LOG2E; bhn2[3] = b2.w * TWO_LOG2E;
    }

    float h[4] = {0.f, 0.f, 0.f, 0.f};
    *(uint2*)&zbuf[0][l15][fbase] = pack4(0.f, 0.f, 0.f, 0.f);
    int p = 0;
    __syncthreads();

    const f32x4_t z4 = {0.f, 0.f, 0.f, 0.f};

    if (role == 1) {
        // GRU0: gh accumulators (2 per gate) computed pre-poll; gx MFMAs seed
        // from them via the C-operand (gates r,z) -> post-ax chain = 2 MFMA + 1
        // add + exp2-form activations. n-gate gh kept separate (scaled by rr).
#pragma unroll 1
        for (int t = 0; t < TPTS; ++t) {
            bf16x8_t ah[4];
#pragma unroll
            for (int kt = 0; kt < 4; ++kt)
                ah[kt] = ldfrag(&zbuf[p][l15][kt * 32 + quad * 8]);
            f32x4_t ghA[3], ghB[3];
#pragma unroll
            for (int g = 0; g < 3; ++g) {
                ghA[g] = mfma16(whh[g][0], ah[0], z4);
                ghA[g] = mfma16(whh[g][1], ah[1], ghA[g]);
                ghB[g] = mfma16(whh[g][2], ah[2], z4);
                ghB[g] = mfma16(whh[g][3], ah[3], ghB[g]);
            }
            // off-chain: n-gate h-part folded to t1s = fmaf(ghc2, 2log2e, bhn2)
            f32x4_t ghc2 = ghA[2] + ghB[2];
            float t1s[4];
#pragma unroll
            for (int i = 0; i < 4; ++i) t1s[i] = fmaf(ghc2[i], TWO_LOG2E, bhn2[i]);

            asm volatile("s_waitcnt vmcnt(0)" ::: "memory");   // drain t-1 h1 store
            __builtin_amdgcn_s_barrier();                      // all waves drained
            if (tid == 0) {
                if (t > 0)
                    __hip_atomic_store(&h1flag[c * 128 + (t - 1)], H1MAGIC(t - 1),
                                       __ATOMIC_RELAXED, __HIP_MEMORY_SCOPE_AGENT);
                int guard = 0;
                while (__hip_atomic_load(&yflag[c * 128 + t],
                                         __ATOMIC_RELAXED, __HIP_MEMORY_SCOPE_AGENT) != YMAGIC(t)) {
                    __builtin_amdgcn_s_sleep(1);
                    if (++guard > (1 << 22)) break;
                }
            }
            __syncthreads();
            const unsigned short* xp = src + ((size_t)t * 1024 + rbase + l15) * CTOT;
            bf16x8_t ax[4];
#pragma unroll
            for (int kt = 0; kt < 4; ++kt) ax[kt] = ldfragG(xp + kt * 32 + quad * 8);
            // gx seeded with gh (r,z gates); n-gate from zero seeds
            f32x4_t gA0 = mfma16(wih[0][0], ax[0], ghA[0]);
            gA0 = mfma16(wih[0][1], ax[1], gA0);
            f32x4_t gB0 = mfma16(wih[0][2], ax[2], ghB[0]);
            gB0 = mfma16(wih[0][3], ax[3], gB0);
            f32x4_t gA1 = mfma16(wih[1][0], ax[0], ghA[1]);
            gA1 = mfma16(wih[1][1], ax[1], gA1);
            f32x4_t gB1 = mfma16(wih[1][2], ax[2], ghB[1]);
            gB1 = mfma16(wih[1][3], ax[3], gB1);
            f32x4_t gA2 = mfma16(wih[2][0], ax[0], z4);
            gA2 = mfma16(wih[2][1], ax[1], gA2);
            f32x4_t gB2 = mfma16(wih[2][2], ax[2], z4);
            gB2 = mfma16(wih[2][3], ax[3], gB2);
            f32x4_t s0 = gA0 + gB0, s1 = gA1 + gB1, s2 = gA2 + gB2;
#pragma unroll
            for (int i = 0; i < 4; ++i) {
                float er = __builtin_amdgcn_exp2f(fmaf(s0[i], NLOG2E, brl[i]));
                float rr = __builtin_amdgcn_rcpf(er + 1.f);
                float ez = __builtin_amdgcn_exp2f(fmaf(s1[i], NLOG2E, bzl[i]));
                float zg = __builtin_amdgcn_rcpf(ez + 1.f);
                float t0s = fmaf(s2[i], TWO_LOG2E, bin2[i]);
                float en = __builtin_amdgcn_exp2f(fmaf(rr, t1s[i], t0s));
                float rn = __builtin_amdgcn_rcpf(en + 1.f);
                float nn = fmaf(-2.f, rn, 1.f);
                h[i] = fmaf(zg, h[i] - nn, nn);
            }
            uint2 pk = pack4(h[0], h[1], h[2], h[3]);
            *(uint2*)&zbuf[p ^ 1][l15][fbase] = pk;
            stg8(h1Traj + ((size_t)t * 1024 + rbase + l15) * CTOT + fbase, pk);
            LGKM_BAR();          // LDS handoff only; h1 store drains next iter
            p ^= 1;
        }
        asm volatile("s_waitcnt vmcnt(0)" ::: "memory");
        __syncthreads();
        if (tid == 0)
            __hip_atomic_store(&h1flag[c * 128 + (TPTS - 1)], H1MAGIC(TPTS - 1),
                               __ATOMIC_RELAXED, __HIP_MEMORY_SCOPE_AGENT);
        return;
    }

    // role 2: GRU1 (no global stores in loop) + MLP head — same cell shave
#pragma unroll 1
    for (int t = 0; t < TPTS; ++t) {
        waitflag(&sflag[c * 128 + t], H1MAGIC(t));
        const unsigned short* xp = src + ((size_t)t * 1024 + rbase + l15) * CTOT;
        bf16x8_t ax[4], ah[4];
#pragma unroll
        for (int kt = 0; kt < 4; ++kt) {
            ax[kt] = ldfragG(xp + kt * 32 + quad * 8);
            ah[kt] = ldfrag(&zbuf[p][l15][kt * 32 + quad * 8]);
        }
        // gh first (LDS data arrives before LLC ax), then gx seeds from it
        f32x4_t ghA[3], ghB[3];
#pragma unroll
        for (int g = 0; g < 3; ++g) {
            ghA[g] = mfma16(whh[g][0], ah[0], z4);
            ghA[g] = mfma16(whh[g][1], ah[1], ghA[g]);
            ghB[g] = mfma16(whh[g][2], ah[2], z4);
            ghB[g] = mfma16(whh[g][3], ah[3], ghB[g]);
        }
        f32x4_t ghc2 = ghA[2] + ghB[2];
        float t1s[4];
#pragma unroll
        for (int i = 0; i < 4; ++i) t1s[i] = fmaf(ghc2[i], TWO_LOG2E, bhn2[i]);
        f32x4_t gA0 = mfma16(wih[0][0], ax[0], ghA[0]);
        gA0 = mfma16(wih[0][1], ax[1], gA0);
        f32x4_t gB0 = mfma16(wih[0][2], ax[2], ghB[0]);
        gB0 = mfma16(wih[0][3], ax[3], gB0);
        f32x4_t gA1 = mfma16(wih[1][0], ax[0], ghA[1]);
        gA1 = mfma16(wih[1][1], ax[1], gA1);
        f32x4_t gB1 = mfma16(wih[1][2], ax[2], ghB[1]);
        gB1 = mfma16(wih[1][3], ax[3], gB1);
        f32x4_t gA2 = mfma16(wih[2][0], ax[0], z4);
        gA2 = mfma16(wih[2][1], ax[1], gA2);
        f32x4_t gB2 = mfma16(wih[2][2], ax[2], z4);
        gB2 = mfma16(wih[2][3], ax[3], gB2);
        f32x4_t s0 = gA0 + gB0, s1 = gA1 + gB1, s2 = gA2 + gB2;
#pragma unroll
        for (int i = 0; i < 4; ++i) {
            float er = __builtin_amdgcn_exp2f(fmaf(s0[i], NLOG2E, brl[i]));
            float rr = __builtin_amdgcn_rcpf(er + 1.f);
            float ez = __builtin_amdgcn_exp2f(fmaf(s1[i], NLOG2E, bzl[i]));
            float zg = __builtin_amdgcn_rcpf(ez + 1.f);
            float t0s = fmaf(s2[i], TWO_LOG2E, bin2[i]);
            float en = __builtin_amdgcn_exp2f(fmaf(rr, t1s[i], t0s));
            float rn = __builtin_amdgcn_rcpf(en + 1.f);
            float nn = fmaf(-2.f, rn, 1.f);
            h[i] = fmaf(zg, h[i] - nn, nn);
        }
        *(uint2*)&zbuf[p ^ 1][l15][fbase] = pack4(h[0], h[1], h[2], h[3]);
        LGKM_BAR();
        p ^= 1;
    }

    // ==================== MLP head (role 2) ===================================
    if (wv < 4) {
        bf16x8_t wf[4], hf[4];
#pragma unroll
        for (int kt = 0; kt < 4; ++kt) {
            wf[kt] = ldfragW(W1v + (size_t)(wv * 16 + l15) * CTOT + kt * 32 + quad * 8);
            hf[kt] = ldfrag(&zbuf[p][l15][kt * 32 + quad * 8]);
        }
        f32x4_t acc = {0.f, 0.f, 0.f, 0.f};
#pragma unroll
        for (int kt = 0; kt < 4; ++kt) acc = mfma16(wf[kt], hf[kt], acc);
        float4 bb = *(const float4*)(b1v + wv * 16 + quad * 4);
        const float* bbp = (const float*)&bb;
        float gl[4];
#pragma unroll
        for (int i = 0; i < 4; ++i) {
            float x = acc[i] + bbp[i];
            gl[i] = 0.5f * x * (1.0f + erff(x * 0.70710678118654752f));
        }
        *(uint2*)&hidbuf[l15][wv * 16 + quad * 4] = pack4(gl[0], gl[1], gl[2], gl[3]);
    }
    __syncthreads();

    bf16x8_t ahid[2];
#pragma unroll
    for (int kt = 0; kt < 2; ++kt)
        ahid[kt] = ldfrag(&hidbuf[l15][kt * 32 + quad * 8]);
#pragma unroll 1
    for (int j = 0; j < 24; ++j) {
        int mt2 = wv * 24 + j;
        bf16x8_t wf0 = ldfragW(W2v + (size_t)(mt2 * 16 + l15) * 64 + quad * 8);
        bf16x8_t wf1 = ldfragW(W2v + (size_t)(mt2 * 16 + l15) * 64 + 32 + quad * 8);
        float4 bv = *(const float4*)(b2v + mt2 * 16 + quad * 4);
        const float* bvp = (const float*)&bv;
        f32x4_t acc = {0.f, 0.f, 0.f, 0.f};
        acc = mfma16(wf0, ahid[0], acc);
        acc = mfma16(wf1, ahid[1], acc);
        float4 o;
        o.x = acc[0] + bvp[0]; o.y = acc[1] + bvp[1];
        o.z = acc[2] + bvp[2]; o.w = acc[3] + bvp[3];
        *(float4*)(outp + (size_t)(rbase + l15) * 3072 + mt2 * 16 + quad * 4) = o;
    }
#undef YMAGIC
#undef H1MAGIC
}

extern "C" void kernel_launch(void* const* d_in, const int* in_sizes, int n_in,
                              void* d_out, int out_size, void* d_ws, size_t ws_size,
                              hipStream_t stream) {
    // setup_inputs order: 0:x(unused) 1:yl 2:yh 3:W_ode 4:b_ode 5:W_ih0 6:W_hh0
    // 7:b_ih0 8:b_hh0 9:W_ih1 10:W_hh1 11:b_ih1 12:b_hh1 13:W1 14:b1 15:W2 16:b2
    const float* yl   = (const float*)d_in[1];
    const float* yh   = (const float*)d_in[2];
    const float* Wode = (const float*)d_in[3];
    const float* bode = (const float*)d_in[4];
    const float* Wih0 = (const float*)d_in[5];
    const float* Whh0 = (const float*)d_in[6];
    const float* bih0 = (const float*)d_in[7];
    const float* bhh0 = (const float*)d_in[8];
    const float* Wih1 = (const float*)d_in[9];
    const float* Whh1 = (const float*)d_in[10];
    const float* bih1 = (const float*)d_in[11];
    const float* bhh1 = (const float*)d_in[12];
    const float* W1v  = (const float*)d_in[13];
    const float* b1v  = (const float*)d_in[14];
    const float* W2v  = (const float*)d_in[15];
    const float* b2v  = (const float*)d_in[16];

    ode_forecaster<<<dim3(192), dim3(512), 0, stream>>>(
        yl, yh, Wode, bode, Wih0, Whh0, bih0, bhh0,
        Wih1, Whh1, bih1, bhh1, W1v, b1v, W2v, b2v,
        (float*)d_out, (char*)d_ws);
}